// Round 15
// baseline (59.486 us; speedup 1.0000x reference)
//
#include <hip/hip_runtime.h>
#include <math.h>

#define BATCH 8
#define CH    128
#define HH    64
#define WW    64
#define HWSZ  (HH*WW)        // 4096
#define KK    9
#define OC27  27
#define KDIM  1152           // CH*KK

typedef unsigned short ushort_t;
typedef unsigned int   uint_t;
typedef __attribute__((ext_vector_type(8))) short  short8v;
typedef __attribute__((ext_vector_type(4))) float  float4v;

__device__ __forceinline__ float bf2f(uint_t u16) {        // low 16 bits = bf16
    return __uint_as_float(u16 << 16);
}
__device__ __forceinline__ float bf2f_hi(uint_t u) {       // high half of packed pair
    return __uint_as_float(u & 0xffff0000u);
}
__device__ __forceinline__ ushort_t f2bf(float f) {        // RNE
    uint_t u = __float_as_uint(f);
    return (ushort_t)((u + 0x7fffu + ((u >> 16) & 1u)) >> 16);
}

// ---------------- K0: merged prep (transpose x + both weight packs) ----------------
__global__ __launch_bounds__(256) void k_prep_all(const float* __restrict__ in,
                                                  const float* __restrict__ weight,
                                                  const float* __restrict__ offset_w,
                                                  const float* __restrict__ mask_w,
                                                  ushort_t* __restrict__ x_bf,
                                                  ushort_t* __restrict__ w2,
                                                  ushort_t* __restrict__ w2om) {
    __shared__ float tile[32][33];
    int bid = blockIdx.x;
    int tid = threadIdx.x;
    if (bid < 4096) {
        int bx = bid & 127, by = (bid >> 7) & 3, bz = bid >> 9;
        int s0 = bx * 32, c0 = by * 32, b = bz;
        int tx = tid & 31, ty = tid >> 5;
        const float* inb = in   + (size_t)b * CH * HWSZ;
        ushort_t*   outb = x_bf + (size_t)b * HWSZ * CH;
#pragma unroll
        for (int i = 0; i < 32; i += 8)
            tile[ty + i][tx] = inb[(size_t)(c0 + ty + i) * HWSZ + s0 + tx];
        __syncthreads();
#pragma unroll
        for (int i = 0; i < 32; i += 8)
            outb[(size_t)(s0 + ty + i) * CH + c0 + tx] = f2bf(tile[tx][ty + i]);
    } else {
        int e = (bid - 4096) * 256 + tid;
        if (e < CH * KDIM) {
            int oc  = e / KDIM;
            int rem = e - oc * KDIM;
            int c   = rem / KK;
            int t   = rem - c * KK;
            int k_lin = (c >> 5) * 288 + t * 32 + (c & 31);
            w2[(size_t)(k_lin >> 3) * (CH * 8) + oc * 8 + (k_lin & 7)] = f2bf(weight[e]);
        } else if (e < CH * KDIM + 32 * KDIM) {
            int e2  = e - CH * KDIM;
            int oc  = e2 / KDIM;
            int rem = e2 - oc * KDIM;
            int c   = rem / KK;
            int t   = rem - c * KK;
            float v = 0.f;
            if (oc < 18)      v = offset_w[(size_t)oc * KDIM + rem];
            else if (oc < 27) v = mask_w[(size_t)(oc - 18) * KDIM + rem];
            int k_lin = (c >> 5) * 288 + t * 32 + (c & 31);
            w2om[(size_t)(k_lin >> 3) * (32 * 8) + oc * 8 + (k_lin & 7)] = f2bf(v);
        }
    }
}

// ---------------- Fused: offmask conv + params + deform gather + main GEMM ----------------
#define DP   64      // pixels per block (one full image row)
#define RSE  320     // LDS row stride in bf16 elems (640 B)
#define NT   512     // 8 waves, all uniform (no wave gating anywhere)

// element-index swizzle: off ^= (row&7)<<3  (flips elem bits 3-5, stays 16B-aligned)
__device__ __forceinline__ int swz(int row, int off) { return off ^ ((row & 7) << 3); }

__global__ __launch_bounds__(NT) void k_fused(
        const ushort_t* __restrict__ x_bf,
        const ushort_t* __restrict__ w2,
        const ushort_t* __restrict__ w2om,
        const float* __restrict__ offset_b, const float* __restrict__ mask_b,
        const float* __restrict__ bias,
        float* __restrict__ out) {
    __shared__ ushort_t s[DP * RSE];       // 40,960 B
    __shared__ float    psf[2880];         // 11,520 B: om[64][27] -> wq[576][4] + enc[576]

    int tid = threadIdx.x;
    int p0  = blockIdx.x * DP;
    int b   = p0 >> 12;
    int h   = (p0 >> 6) & 63;
    int wid = tid >> 6, lane = tid & 63;
    int lh  = lane >> 4, ll = lane & 15;

    const ushort_t* xb_img = x_bf + ((size_t)b * HWSZ * CH);

    // ============ Phase 1: offset/mask conv via MFMA (8 uniform waves) ============
    // tiles: pixT = wid&3 (16 pix), ocT = wid>>2 (16 oc of the 32-col panel)
    int pixT = wid & 3, ocT = wid >> 2;
    float4v acc1 = (float4v){0.f, 0.f, 0.f, 0.f};

    for (int chunk = 0; chunk < 4; ++chunk) {
        int c0 = chunk * 32;
        for (int v = tid; v < DP * KK * 4; v += NT) {
            int t   = v >> 8;
            int r   = v & 255;
            int pix = r >> 2, cg = r & 3;
            int y   = h + t / 3 - 1;
            int x   = pix + t % 3 - 1;
            uint4 u = make_uint4(0u, 0u, 0u, 0u);
            if (y >= 0 && y < HH && x >= 0 && x < WW)
                u = *(const uint4*)(xb_img + (size_t)(y * WW + x) * CH + c0 + cg * 8);
            *(uint4*)(&s[pix * RSE + swz(pix, t * 32 + cg * 8)]) = u;
        }
        __syncthreads();

        const ushort_t* wb = w2om + (size_t)chunk * 36 * 256;
#pragma unroll 3
        for (int ks = 0; ks < 9; ++ks) {
            int row = pixT * 16 + ll;
            short8v a = *(const short8v*)(&s[row * RSE + swz(row, ks * 32 + lh * 8)]);
            const ushort_t* wp = wb + (ks * 4 + lh) * 256 + (ocT * 16 + ll) * 8;
            short8v bfr = *(const short8v*)(wp);
            acc1 = __builtin_amdgcn_mfma_f32_16x16x32_bf16(a, bfr, acc1, 0, 0, 0);
        }
        __syncthreads();
    }

    // epilogue -> om in psf[pix*27 + oc]  (all 8 waves; lanes with oc>=27 skip)
    {
        int oc = ocT * 16 + ll;
        if (oc < OC27) {
            float bv = (oc < 18) ? offset_b[oc] : mask_b[oc - 18];
#pragma unroll
            for (int r = 0; r < 4; ++r) {
                int pix = pixT * 16 + lh * 4 + r;
                float vv = acc1[r] + bv;
                if (oc >= 18) vv = 1.f / (1.f + expf(-vv));
                psf[pix * 27 + oc] = vv;
            }
        }
    }
    __syncthreads();

    // ============ Phase A: bilinear params (576 items, 512 threads) ============
    float dy0, dx0, m0, dy2 = 0.f, dx2 = 0.f, m2 = 0.f;
    {
        int pA = tid / 9, tA = tid - pA * 9;
        dy0 = psf[pA * 27 + 2 * tA]; dx0 = psf[pA * 27 + 2 * tA + 1]; m0 = psf[pA * 27 + 18 + tA];
        if (tid < 64) {
            int v2 = tid + NT, pC = v2 / 9, tC = v2 - pC * 9;
            dy2 = psf[pC * 27 + 2 * tC]; dx2 = psf[pC * 27 + 2 * tC + 1]; m2 = psf[pC * 27 + 18 + tC];
        }
    }
    __syncthreads();

    uint_t* enc = (uint_t*)(psf + 2304);
#define PARAM_STORE(v, dy, dx, m) {                                             \
        int pix = (v) / 9, t = (v) - pix * 9;                                   \
        float py = (float)(h + t / 3 - 1) + (dy);                               \
        float px = (float)(pix + t % 3 - 1) + (dx);                             \
        float y0f = floorf(py), x0f = floorf(px);                               \
        float ly = py - y0f, lx = px - x0f;                                     \
        int y0 = (int)y0f, x0 = (int)x0f;                                       \
        int y1 = y0 + 1,   x1 = x0 + 1;                                         \
        bool vy0 = (y0 >= 0) & (y0 < HH), vy1 = (y1 >= 0) & (y1 < HH);          \
        bool vx0 = (x0 >= 0) & (x0 < WW), vx1 = (x1 >= 0) & (x1 < WW);          \
        int yc0 = min(max(y0, 0), HH - 1), yc1 = min(max(y1, 0), HH - 1);       \
        int xc0 = min(max(x0, 0), WW - 1), xc1 = min(max(x1, 0), WW - 1);       \
        int idx00 = (yc0 * WW + xc0) * CH;                                      \
        enc[v] = (uint_t)idx00 | ((uint_t)(xc1 - xc0) << 30)                    \
                               | ((uint_t)(yc1 - yc0) << 31);                   \
        float4 wq;                                                              \
        wq.x = (1.f - ly) * (1.f - lx) * (m) * ((vy0 && vx0) ? 1.f : 0.f);      \
        wq.y = (1.f - ly) * lx         * (m) * ((vy0 && vx1) ? 1.f : 0.f);      \
        wq.z = ly         * (1.f - lx) * (m) * ((vy1 && vx0) ? 1.f : 0.f);      \
        wq.w = ly         * lx         * (m) * ((vy1 && vx1) ? 1.f : 0.f);      \
        *(float4*)(&psf[(v) * 4]) = wq;                                         \
    }
    PARAM_STORE(tid, dy0, dx0, m0);
    if (tid < 64) PARAM_STORE(tid + NT, dy2, dx2, m2);
#undef PARAM_STORE
    __syncthreads();

    // ============ Phase 2: deformed gather + main MFMA (8 uniform waves) ============
    int wr = wid & 3;            // pixel quarter (16 pix)
    int wc = wid >> 2;           // oc half (64 oc)
    float4v acc[4];
#pragma unroll
    for (int j = 0; j < 4; j++)
        acc[j] = (float4v){0.f, 0.f, 0.f, 0.f};

    for (int chunk = 0; chunk < 4; ++chunk) {
        int c0 = chunk * 32;
        for (int v = tid; v < DP * KK * 4; v += NT) {
            int t   = v >> 8;
            int r   = v & 255;
            int pix = r >> 2, cg = r & 3;
            int pv  = pix * 9 + t;
            uint_t e  = enc[pv];
            float4 wq = *(const float4*)(&psf[pv * 4]);
            int idx00 = (int)(e & 0x3FFFFFFFu);
            int dxo   = (int)((e >> 30) & 1u) << 7;    // +CH
            int dyo   = (int)(e >> 31) << 13;          // +WW*CH
            const ushort_t* bp = xb_img + idx00 + c0 + cg * 8;
            uint4 u00 = *(const uint4*)(bp);
            uint4 u01 = *(const uint4*)(bp + dxo);
            uint4 u10 = *(const uint4*)(bp + dyo);
            uint4 u11 = *(const uint4*)(bp + dxo + dyo);
            uint4 res;
#define CMB(fld) {                                                         \
            float lo = wq.x * bf2f(u00.fld & 0xffffu);                     \
            lo = fmaf(wq.y, bf2f(u01.fld & 0xffffu), lo);                  \
            lo = fmaf(wq.z, bf2f(u10.fld & 0xffffu), lo);                  \
            lo = fmaf(wq.w, bf2f(u11.fld & 0xffffu), lo);                  \
            float hi = wq.x * bf2f_hi(u00.fld);                            \
            hi = fmaf(wq.y, bf2f_hi(u01.fld), hi);                        \
            hi = fmaf(wq.z, bf2f_hi(u10.fld), hi);                        \
            hi = fmaf(wq.w, bf2f_hi(u11.fld), hi);                        \
            res.fld = (uint_t)f2bf(lo) | ((uint_t)f2bf(hi) << 16); }
            CMB(x); CMB(y); CMB(z); CMB(w);
#undef CMB
            *(uint4*)(&s[pix * RSE + swz(pix, t * 32 + cg * 8)]) = res;
        }
        __syncthreads();

        const ushort_t* wb = w2 + (size_t)chunk * 36 * 1024;
        __builtin_amdgcn_s_setprio(1);
#pragma unroll 3
        for (int ks = 0; ks < 9; ++ks) {
            int rowA = wr * 16 + ll;
            short8v a0 = *(const short8v*)(&s[rowA * RSE + swz(rowA, ks * 32 + lh * 8)]);
            const ushort_t* wp = wb + (ks * 4 + lh) * 1024 + (wc * 64 + ll) * 8;
            short8v b0 = *(const short8v*)(wp);
            short8v b1 = *(const short8v*)(wp + 128);
            short8v b2 = *(const short8v*)(wp + 256);
            short8v b3 = *(const short8v*)(wp + 384);
            acc[0] = __builtin_amdgcn_mfma_f32_16x16x32_bf16(a0, b0, acc[0], 0, 0, 0);
            acc[1] = __builtin_amdgcn_mfma_f32_16x16x32_bf16(a0, b1, acc[1], 0, 0, 0);
            acc[2] = __builtin_amdgcn_mfma_f32_16x16x32_bf16(a0, b2, acc[2], 0, 0, 0);
            acc[3] = __builtin_amdgcn_mfma_f32_16x16x32_bf16(a0, b3, acc[3], 0, 0, 0);
        }
        __builtin_amdgcn_s_setprio(0);
        __syncthreads();
    }

    // Epilogue: D col(oc)=ll, row(pix)=lh*4+reg
#pragma unroll
    for (int oj = 0; oj < 4; ++oj) {
        int oc = wc * 64 + oj * 16 + ll;
        int w  = wr * 16 + lh * 4;
        float bv = bias[oc];
        float4v a = acc[oj];
        float* op = out + (((size_t)(b * CH + oc)) << 12) + (h << 6) + w;
        *(float4*)op = make_float4(a[0] + bv, a[1] + bv, a[2] + bv, a[3] + bv);
    }
}

extern "C" void kernel_launch(void* const* d_in, const int* in_sizes, int n_in,
                              void* d_out, int out_size, void* d_ws, size_t ws_size,
                              hipStream_t stream) {
    const float* x        = (const float*)d_in[0];
    const float* offset_w = (const float*)d_in[1];
    const float* offset_b = (const float*)d_in[2];
    const float* mask_w   = (const float*)d_in[3];
    const float* mask_b   = (const float*)d_in[4];
    const float* weight   = (const float*)d_in[5];
    const float* bias     = (const float*)d_in[6];
    float* out = (float*)d_out;

    char* ws = (char*)d_ws;
    ushort_t* x_bf = (ushort_t*)ws;                        // 8,388,608 B
    ushort_t* w2   = (ushort_t*)(ws + 8388608);            //   294,912 B
    ushort_t* w2om = (ushort_t*)(ws + 8388608 + 294912);   //    73,728 B

    int wblocks = ((CH + 32) * KDIM + 255) / 256;          // 720
    k_prep_all<<<4096 + wblocks, 256, 0, stream>>>(x, weight, offset_w, mask_w,
                                                   x_bf, w2, w2om);

    int npix = BATCH * HWSZ;                               // 32768
    k_fused<<<npix / DP, NT, 0, stream>>>(x_bf, w2, w2om, offset_b, mask_b, bias, out);
}

// Round 16
// 57.434 us; speedup vs baseline: 1.0357x; 1.0357x over previous
//
#include <hip/hip_runtime.h>
#include <math.h>

#define BATCH 8
#define CH    128
#define HH    64
#define WW    64
#define HWSZ  (HH*WW)        // 4096
#define KK    9
#define OC27  27
#define KDIM  1152           // CH*KK

typedef unsigned short ushort_t;
typedef unsigned int   uint_t;
typedef __attribute__((ext_vector_type(8))) short  short8v;
typedef __attribute__((ext_vector_type(4))) float  float4v;

__device__ __forceinline__ float bf2f(uint_t u16) {        // low 16 bits = bf16
    return __uint_as_float(u16 << 16);
}
__device__ __forceinline__ float bf2f_hi(uint_t u) {       // high half of packed pair
    return __uint_as_float(u & 0xffff0000u);
}
__device__ __forceinline__ ushort_t f2bf(float f) {        // RNE
    uint_t u = __float_as_uint(f);
    return (ushort_t)((u + 0x7fffu + ((u >> 16) & 1u)) >> 16);
}

// ---------------- K0: merged prep (transpose x + both weight packs) ----------------
__global__ __launch_bounds__(256) void k_prep_all(const float* __restrict__ in,
                                                  const float* __restrict__ weight,
                                                  const float* __restrict__ offset_w,
                                                  const float* __restrict__ mask_w,
                                                  ushort_t* __restrict__ x_bf,
                                                  ushort_t* __restrict__ w2,
                                                  ushort_t* __restrict__ w2om) {
    __shared__ float tile[32][33];
    int bid = blockIdx.x;
    int tid = threadIdx.x;
    if (bid < 4096) {
        int bx = bid & 127, by = (bid >> 7) & 3, bz = bid >> 9;
        int s0 = bx * 32, c0 = by * 32, b = bz;
        int tx = tid & 31, ty = tid >> 5;
        const float* inb = in   + (size_t)b * CH * HWSZ;
        ushort_t*   outb = x_bf + (size_t)b * HWSZ * CH;
#pragma unroll
        for (int i = 0; i < 32; i += 8)
            tile[ty + i][tx] = inb[(size_t)(c0 + ty + i) * HWSZ + s0 + tx];
        __syncthreads();
#pragma unroll
        for (int i = 0; i < 32; i += 8)
            outb[(size_t)(s0 + ty + i) * CH + c0 + tx] = f2bf(tile[tx][ty + i]);
    } else {
        int e = (bid - 4096) * 256 + tid;
        if (e < CH * KDIM) {
            int oc  = e / KDIM;
            int rem = e - oc * KDIM;
            int c   = rem / KK;
            int t   = rem - c * KK;
            int k_lin = (c >> 5) * 288 + t * 32 + (c & 31);
            w2[(size_t)(k_lin >> 3) * (CH * 8) + oc * 8 + (k_lin & 7)] = f2bf(weight[e]);
        } else if (e < CH * KDIM + 32 * KDIM) {
            int e2  = e - CH * KDIM;
            int oc  = e2 / KDIM;
            int rem = e2 - oc * KDIM;
            int c   = rem / KK;
            int t   = rem - c * KK;
            float v = 0.f;
            if (oc < 18)      v = offset_w[(size_t)oc * KDIM + rem];
            else if (oc < 27) v = mask_w[(size_t)(oc - 18) * KDIM + rem];
            int k_lin = (c >> 5) * 288 + t * 32 + (c & 31);
            w2om[(size_t)(k_lin >> 3) * (32 * 8) + oc * 8 + (k_lin & 7)] = f2bf(v);
        }
    }
}

// ---------------- Fused: offmask conv + params + deform gather + main GEMM ----------------
#define DP   64      // pixels per block (one full image row)
#define RSE  320     // LDS row stride in bf16 elems (640 B)
#define NT   512     // 8 waves, all uniform (no wave gating anywhere)
#define CPAD 40      // phase-1 raw-tile channel stride (80 B, 16B-aligned)

// element-index swizzle: off ^= (row&7)<<3  (flips elem bits 3-5, stays 16B-aligned)
__device__ __forceinline__ int swz(int row, int off) { return off ^ ((row & 7) << 3); }

__global__ __launch_bounds__(NT) void k_fused(
        const ushort_t* __restrict__ x_bf,
        const ushort_t* __restrict__ w2,
        const ushort_t* __restrict__ w2om,
        const float* __restrict__ offset_b, const float* __restrict__ mask_b,
        const float* __restrict__ bias,
        float* __restrict__ out) {
    __shared__ ushort_t s[DP * RSE];       // 40,960 B (phase-1 raw tile reuses first 15,840 B)
    __shared__ float    psf[2880];         // 11,520 B: om[64][27] -> wq[576][4] + enc[576]

    int tid = threadIdx.x;
    int p0  = blockIdx.x * DP;
    int b   = p0 >> 12;
    int h   = (p0 >> 6) & 63;
    int wid = tid >> 6, lane = tid & 63;
    int lh  = lane >> 4, ll = lane & 15;

    const ushort_t* xb_img = x_bf + ((size_t)b * HWSZ * CH);

    // ============ Phase 1: offset/mask conv via MFMA (8 uniform waves) ============
    // Raw 3-row tile: s[(yr*66 + col)*CPAD + c] = x[h+yr-1, col-1, c0+c] (zero-padded).
    // A-frag for tap ks = rows yr=ks/3, cols pix + ks%3 — same values as im2col form.
    int pixT = wid & 3, ocT = wid >> 2;
    float4v acc1 = (float4v){0.f, 0.f, 0.f, 0.f};

    for (int chunk = 0; chunk < 4; ++chunk) {
        int c0 = chunk * 32;
        for (int v = tid; v < 3 * 66 * 4; v += NT) {    // 792 items
            int yr  = v / 264;
            int r   = v - yr * 264;
            int col = r >> 2, cg = r & 3;
            int y   = h + yr - 1;
            int x   = col - 1;
            uint4 u = make_uint4(0u, 0u, 0u, 0u);
            if (y >= 0 && y < HH && x >= 0 && x < WW)
                u = *(const uint4*)(xb_img + (size_t)(y * WW + x) * CH + c0 + cg * 8);
            *(uint4*)(&s[(yr * 66 + col) * CPAD + cg * 8]) = u;
        }
        __syncthreads();

        const ushort_t* wb = w2om + (size_t)chunk * 36 * 256;
#pragma unroll
        for (int ks = 0; ks < 9; ++ks) {
            int yr = ks / 3, dx = ks % 3;               // constants after unroll
            int col = pixT * 16 + ll + dx;
            short8v a = *(const short8v*)(&s[(yr * 66 + col) * CPAD + lh * 8]);
            const ushort_t* wp = wb + (ks * 4 + lh) * 256 + (ocT * 16 + ll) * 8;
            short8v bfr = *(const short8v*)(wp);
            acc1 = __builtin_amdgcn_mfma_f32_16x16x32_bf16(a, bfr, acc1, 0, 0, 0);
        }
        __syncthreads();
    }

    // epilogue -> om in psf[pix*27 + oc]  (all 8 waves; lanes with oc>=27 skip)
    {
        int oc = ocT * 16 + ll;
        if (oc < OC27) {
            float bv = (oc < 18) ? offset_b[oc] : mask_b[oc - 18];
#pragma unroll
            for (int r = 0; r < 4; ++r) {
                int pix = pixT * 16 + lh * 4 + r;
                float vv = acc1[r] + bv;
                if (oc >= 18) vv = 1.f / (1.f + expf(-vv));
                psf[pix * 27 + oc] = vv;
            }
        }
    }
    __syncthreads();

    // ============ Phase A: bilinear params (576 items, 512 threads) ============
    float dy0, dx0, m0, dy2 = 0.f, dx2 = 0.f, m2 = 0.f;
    {
        int pA = tid / 9, tA = tid - pA * 9;
        dy0 = psf[pA * 27 + 2 * tA]; dx0 = psf[pA * 27 + 2 * tA + 1]; m0 = psf[pA * 27 + 18 + tA];
        if (tid < 64) {
            int v2 = tid + NT, pC = v2 / 9, tC = v2 - pC * 9;
            dy2 = psf[pC * 27 + 2 * tC]; dx2 = psf[pC * 27 + 2 * tC + 1]; m2 = psf[pC * 27 + 18 + tC];
        }
    }
    __syncthreads();

    uint_t* enc = (uint_t*)(psf + 2304);
#define PARAM_STORE(v, dy, dx, m) {                                             \
        int pix = (v) / 9, t = (v) - pix * 9;                                   \
        float py = (float)(h + t / 3 - 1) + (dy);                               \
        float px = (float)(pix + t % 3 - 1) + (dx);                             \
        float y0f = floorf(py), x0f = floorf(px);                               \
        float ly = py - y0f, lx = px - x0f;                                     \
        int y0 = (int)y0f, x0 = (int)x0f;                                       \
        int y1 = y0 + 1,   x1 = x0 + 1;                                         \
        bool vy0 = (y0 >= 0) & (y0 < HH), vy1 = (y1 >= 0) & (y1 < HH);          \
        bool vx0 = (x0 >= 0) & (x0 < WW), vx1 = (x1 >= 0) & (x1 < WW);          \
        int yc0 = min(max(y0, 0), HH - 1), yc1 = min(max(y1, 0), HH - 1);       \
        int xc0 = min(max(x0, 0), WW - 1), xc1 = min(max(x1, 0), WW - 1);       \
        int idx00 = (yc0 * WW + xc0) * CH;                                      \
        enc[v] = (uint_t)idx00 | ((uint_t)(xc1 - xc0) << 30)                    \
                               | ((uint_t)(yc1 - yc0) << 31);                   \
        float4 wq;                                                              \
        wq.x = (1.f - ly) * (1.f - lx) * (m) * ((vy0 && vx0) ? 1.f : 0.f);      \
        wq.y = (1.f - ly) * lx         * (m) * ((vy0 && vx1) ? 1.f : 0.f);      \
        wq.z = ly         * (1.f - lx) * (m) * ((vy1 && vx0) ? 1.f : 0.f);      \
        wq.w = ly         * lx         * (m) * ((vy1 && vx1) ? 1.f : 0.f);      \
        *(float4*)(&psf[(v) * 4]) = wq;                                         \
    }
    PARAM_STORE(tid, dy0, dx0, m0);
    if (tid < 64) PARAM_STORE(tid + NT, dy2, dx2, m2);
#undef PARAM_STORE
    __syncthreads();

    // ============ Phase 2: deformed gather + main MFMA (8 uniform waves) ============
    int wr = wid & 3;            // pixel quarter (16 pix)
    int wc = wid >> 2;           // oc half (64 oc)
    float4v acc[4];
#pragma unroll
    for (int j = 0; j < 4; j++)
        acc[j] = (float4v){0.f, 0.f, 0.f, 0.f};

    for (int chunk = 0; chunk < 4; ++chunk) {
        int c0 = chunk * 32;
        for (int v = tid; v < DP * KK * 4; v += NT) {
            int t   = v >> 8;
            int r   = v & 255;
            int pix = r >> 2, cg = r & 3;
            int pv  = pix * 9 + t;
            uint_t e  = enc[pv];
            float4 wq = *(const float4*)(&psf[pv * 4]);
            int idx00 = (int)(e & 0x3FFFFFFFu);
            int dxo   = (int)((e >> 30) & 1u) << 7;    // +CH
            int dyo   = (int)(e >> 31) << 13;          // +WW*CH
            const ushort_t* bp = xb_img + idx00 + c0 + cg * 8;
            uint4 u00 = *(const uint4*)(bp);
            uint4 u01 = *(const uint4*)(bp + dxo);
            uint4 u10 = *(const uint4*)(bp + dyo);
            uint4 u11 = *(const uint4*)(bp + dxo + dyo);
            uint4 res;
#define CMB(fld) {                                                         \
            float lo = wq.x * bf2f(u00.fld & 0xffffu);                     \
            lo = fmaf(wq.y, bf2f(u01.fld & 0xffffu), lo);                  \
            lo = fmaf(wq.z, bf2f(u10.fld & 0xffffu), lo);                  \
            lo = fmaf(wq.w, bf2f(u11.fld & 0xffffu), lo);                  \
            float hi = wq.x * bf2f_hi(u00.fld);                            \
            hi = fmaf(wq.y, bf2f_hi(u01.fld), hi);                        \
            hi = fmaf(wq.z, bf2f_hi(u10.fld), hi);                        \
            hi = fmaf(wq.w, bf2f_hi(u11.fld), hi);                        \
            res.fld = (uint_t)f2bf(lo) | ((uint_t)f2bf(hi) << 16); }
            CMB(x); CMB(y); CMB(z); CMB(w);
#undef CMB
            *(uint4*)(&s[pix * RSE + swz(pix, t * 32 + cg * 8)]) = res;
        }
        __syncthreads();

        const ushort_t* wb = w2 + (size_t)chunk * 36 * 1024;
        __builtin_amdgcn_s_setprio(1);
#pragma unroll 3
        for (int ks = 0; ks < 9; ++ks) {
            int rowA = wr * 16 + ll;
            short8v a0 = *(const short8v*)(&s[rowA * RSE + swz(rowA, ks * 32 + lh * 8)]);
            const ushort_t* wp = wb + (ks * 4 + lh) * 1024 + (wc * 64 + ll) * 8;
            short8v b0 = *(const short8v*)(wp);
            short8v b1 = *(const short8v*)(wp + 128);
            short8v b2 = *(const short8v*)(wp + 256);
            short8v b3 = *(const short8v*)(wp + 384);
            acc[0] = __builtin_amdgcn_mfma_f32_16x16x32_bf16(a0, b0, acc[0], 0, 0, 0);
            acc[1] = __builtin_amdgcn_mfma_f32_16x16x32_bf16(a0, b1, acc[1], 0, 0, 0);
            acc[2] = __builtin_amdgcn_mfma_f32_16x16x32_bf16(a0, b2, acc[2], 0, 0, 0);
            acc[3] = __builtin_amdgcn_mfma_f32_16x16x32_bf16(a0, b3, acc[3], 0, 0, 0);
        }
        __builtin_amdgcn_s_setprio(0);
        __syncthreads();
    }

    // Epilogue: D col(oc)=ll, row(pix)=lh*4+reg
#pragma unroll
    for (int oj = 0; oj < 4; ++oj) {
        int oc = wc * 64 + oj * 16 + ll;
        int w  = wr * 16 + lh * 4;
        float bv = bias[oc];
        float4v a = acc[oj];
        float* op = out + (((size_t)(b * CH + oc)) << 12) + (h << 6) + w;
        *(float4*)op = make_float4(a[0] + bv, a[1] + bv, a[2] + bv, a[3] + bv);
    }
}

extern "C" void kernel_launch(void* const* d_in, const int* in_sizes, int n_in,
                              void* d_out, int out_size, void* d_ws, size_t ws_size,
                              hipStream_t stream) {
    const float* x        = (const float*)d_in[0];
    const float* offset_w = (const float*)d_in[1];
    const float* offset_b = (const float*)d_in[2];
    const float* mask_w   = (const float*)d_in[3];
    const float* mask_b   = (const float*)d_in[4];
    const float* weight   = (const float*)d_in[5];
    const float* bias     = (const float*)d_in[6];
    float* out = (float*)d_out;

    char* ws = (char*)d_ws;
    ushort_t* x_bf = (ushort_t*)ws;                        // 8,388,608 B
    ushort_t* w2   = (ushort_t*)(ws + 8388608);            //   294,912 B
    ushort_t* w2om = (ushort_t*)(ws + 8388608 + 294912);   //    73,728 B

    int wblocks = ((CH + 32) * KDIM + 255) / 256;          // 720
    k_prep_all<<<4096 + wblocks, 256, 0, stream>>>(x, weight, offset_w, mask_w,
                                                   x_bf, w2, w2om);

    int npix = BATCH * HWSZ;                               // 32768
    k_fused<<<npix / DP, NT, 0, stream>>>(x_bf, w2, w2om, offset_b, mask_b, bias, out);
}

// Round 17
// 53.856 us; speedup vs baseline: 1.1045x; 1.0664x over previous
//
#include <hip/hip_runtime.h>
#include <math.h>

#define BATCH 8
#define CH    128
#define HH    64
#define WW    64
#define HWSZ  (HH*WW)        // 4096
#define KK    9
#define OC27  27
#define KDIM  1152           // CH*KK

typedef unsigned short ushort_t;
typedef unsigned int   uint_t;
typedef __attribute__((ext_vector_type(8))) short  short8v;
typedef __attribute__((ext_vector_type(4))) float  float4v;

__device__ __forceinline__ float bf2f(uint_t u16) {        // low 16 bits = bf16
    return __uint_as_float(u16 << 16);
}
__device__ __forceinline__ float bf2f_hi(uint_t u) {       // high half of packed pair
    return __uint_as_float(u & 0xffff0000u);
}
__device__ __forceinline__ ushort_t f2bf(float f) {        // RNE
    uint_t u = __float_as_uint(f);
    return (ushort_t)((u + 0x7fffu + ((u >> 16) & 1u)) >> 16);
}

// ---------------- K0: merged prep (transpose x + both weight packs) ----------------
__global__ __launch_bounds__(256) void k_prep_all(const float* __restrict__ in,
                                                  const float* __restrict__ weight,
                                                  const float* __restrict__ offset_w,
                                                  const float* __restrict__ mask_w,
                                                  ushort_t* __restrict__ x_bf,
                                                  ushort_t* __restrict__ w2,
                                                  ushort_t* __restrict__ w2om) {
    __shared__ float tile[32][33];
    int bid = blockIdx.x;
    int tid = threadIdx.x;
    if (bid < 4096) {
        int bx = bid & 127, by = (bid >> 7) & 3, bz = bid >> 9;
        int s0 = bx * 32, c0 = by * 32, b = bz;
        int tx = tid & 31, ty = tid >> 5;
        const float* inb = in   + (size_t)b * CH * HWSZ;
        ushort_t*   outb = x_bf + (size_t)b * HWSZ * CH;
#pragma unroll
        for (int i = 0; i < 32; i += 8)
            tile[ty + i][tx] = inb[(size_t)(c0 + ty + i) * HWSZ + s0 + tx];
        __syncthreads();
#pragma unroll
        for (int i = 0; i < 32; i += 8)
            outb[(size_t)(s0 + ty + i) * CH + c0 + tx] = f2bf(tile[tx][ty + i]);
    } else {
        int e = (bid - 4096) * 256 + tid;
        if (e < CH * KDIM) {
            int oc  = e / KDIM;
            int rem = e - oc * KDIM;
            int c   = rem / KK;
            int t   = rem - c * KK;
            int k_lin = (c >> 5) * 288 + t * 32 + (c & 31);
            w2[(size_t)(k_lin >> 3) * (CH * 8) + oc * 8 + (k_lin & 7)] = f2bf(weight[e]);
        } else if (e < CH * KDIM + 32 * KDIM) {
            int e2  = e - CH * KDIM;
            int oc  = e2 / KDIM;
            int rem = e2 - oc * KDIM;
            int c   = rem / KK;
            int t   = rem - c * KK;
            float v = 0.f;
            if (oc < 18)      v = offset_w[(size_t)oc * KDIM + rem];
            else if (oc < 27) v = mask_w[(size_t)(oc - 18) * KDIM + rem];
            int k_lin = (c >> 5) * 288 + t * 32 + (c & 31);
            w2om[(size_t)(k_lin >> 3) * (32 * 8) + oc * 8 + (k_lin & 7)] = f2bf(v);
        }
    }
}

// ---------------- Fused: offmask conv + params + deform gather + main GEMM ----------------
#define DP   64      // pixels per block (one full image row)
#define RSE  320     // LDS row stride in bf16 elems (640 B)
#define CPAD 40      // phase-1 raw-tile channel stride (80 B, 16B-aligned)

// element-index swizzle: off ^= (row&7)<<3  (flips elem bits 3-5, stays 16B-aligned)
__device__ __forceinline__ int swz(int row, int off) { return off ^ ((row & 7) << 3); }

__global__ __launch_bounds__(256) void k_fused(
        const ushort_t* __restrict__ x_bf,
        const ushort_t* __restrict__ w2,
        const ushort_t* __restrict__ w2om,
        const float* __restrict__ offset_b, const float* __restrict__ mask_b,
        const float* __restrict__ bias,
        float* __restrict__ out) {
    __shared__ ushort_t s[DP * RSE];       // 40,960 B (phase-1 raw tile reuses first 15,840 B)
    __shared__ float    psf[2880];         // 11,520 B: om[64][27] -> wq[576][4] + enc[576]

    int tid = threadIdx.x;
    int p0  = blockIdx.x * DP;
    int b   = p0 >> 12;
    int h   = (p0 >> 6) & 63;
    int wid = tid >> 6, lane = tid & 63;
    int lh  = lane >> 4, ll = lane & 15;

    const ushort_t* xb_img = x_bf + ((size_t)b * HWSZ * CH);

    // ============ Phase 1: offset/mask conv via MFMA (raw 3-row tile) ============
    // s[(yr*66 + col)*CPAD + c] = x[h+yr-1, col-1, c0+c] (zero-padded).
    // A-frag for tap ks: yr=ks/3, col = (wid*16+ll) + ks%3 — same values as im2col form.
    float4v acc1[2];
    acc1[0] = (float4v){0.f, 0.f, 0.f, 0.f};
    acc1[1] = (float4v){0.f, 0.f, 0.f, 0.f};

    for (int chunk = 0; chunk < 4; ++chunk) {
        int c0 = chunk * 32;
        for (int v = tid; v < 3 * 66 * 4; v += 256) {   // 792 items
            int yr  = v / 264;
            int r   = v - yr * 264;
            int col = r >> 2, cg = r & 3;
            int y   = h + yr - 1;
            int x   = col - 1;
            uint4 u = make_uint4(0u, 0u, 0u, 0u);
            if (y >= 0 && y < HH && x >= 0 && x < WW)
                u = *(const uint4*)(xb_img + (size_t)(y * WW + x) * CH + c0 + cg * 8);
            *(uint4*)(&s[(yr * 66 + col) * CPAD + cg * 8]) = u;
        }
        __syncthreads();

        const ushort_t* wb = w2om + (size_t)chunk * 36 * 256;
#pragma unroll
        for (int ks = 0; ks < 9; ++ks) {
            int yr = ks / 3, dx = ks % 3;               // constants after unroll
            int col = wid * 16 + ll + dx;
            short8v a = *(const short8v*)(&s[(yr * 66 + col) * CPAD + lh * 8]);
            const ushort_t* wp = wb + (ks * 4 + lh) * 256 + ll * 8;
            short8v b0 = *(const short8v*)(wp);
            short8v b1 = *(const short8v*)(wp + 128);
            acc1[0] = __builtin_amdgcn_mfma_f32_16x16x32_bf16(a, b0, acc1[0], 0, 0, 0);
            acc1[1] = __builtin_amdgcn_mfma_f32_16x16x32_bf16(a, b1, acc1[1], 0, 0, 0);
        }
        __syncthreads();
    }

    // epilogue -> om in psf[pix*27 + oc]
#pragma unroll
    for (int j = 0; j < 2; ++j) {
        int oc = j * 16 + ll;
        if (oc < OC27) {
            float bv = (oc < 18) ? offset_b[oc] : mask_b[oc - 18];
#pragma unroll
            for (int r = 0; r < 4; ++r) {
                int pix = wid * 16 + lh * 4 + r;
                float vv = acc1[j][r] + bv;
                if (oc >= 18) vv = 1.f / (1.f + expf(-vv));
                psf[pix * 27 + oc] = vv;
            }
        }
    }
    __syncthreads();

    // ============ Phase A: bilinear params (compact) ============
    // items v = tid, tid+256, (tid<64: tid+512);  v -> (pix = v/9, t = v%9)
    float dy0 = 0.f, dx0 = 0.f, m0 = 0.f, dy1 = 0.f, dx1 = 0.f, m1 = 0.f;
    float dy2 = 0.f, dx2 = 0.f, m2 = 0.f;
    {
        int v0 = tid,      pA = v0 / 9, tA = v0 - pA * 9;
        int v1 = tid + 256, pB = v1 / 9, tB = v1 - pB * 9;
        dy0 = psf[pA * 27 + 2 * tA]; dx0 = psf[pA * 27 + 2 * tA + 1]; m0 = psf[pA * 27 + 18 + tA];
        dy1 = psf[pB * 27 + 2 * tB]; dx1 = psf[pB * 27 + 2 * tB + 1]; m1 = psf[pB * 27 + 18 + tB];
        if (tid < 64) {
            int v2 = tid + 512, pC = v2 / 9, tC = v2 - pC * 9;
            dy2 = psf[pC * 27 + 2 * tC]; dx2 = psf[pC * 27 + 2 * tC + 1]; m2 = psf[pC * 27 + 18 + tC];
        }
    }
    __syncthreads();

    uint_t* enc = (uint_t*)(psf + 2304);
#define PARAM_STORE(v, dy, dx, m) {                                             \
        int pix = (v) / 9, t = (v) - pix * 9;                                   \
        float py = (float)(h + t / 3 - 1) + (dy);                               \
        float px = (float)(pix + t % 3 - 1) + (dx);                             \
        float y0f = floorf(py), x0f = floorf(px);                               \
        float ly = py - y0f, lx = px - x0f;                                     \
        int y0 = (int)y0f, x0 = (int)x0f;                                       \
        int y1 = y0 + 1,   x1 = x0 + 1;                                         \
        bool vy0 = (y0 >= 0) & (y0 < HH), vy1 = (y1 >= 0) & (y1 < HH);          \
        bool vx0 = (x0 >= 0) & (x0 < WW), vx1 = (x1 >= 0) & (x1 < WW);          \
        int yc0 = min(max(y0, 0), HH - 1), yc1 = min(max(y1, 0), HH - 1);       \
        int xc0 = min(max(x0, 0), WW - 1), xc1 = min(max(x1, 0), WW - 1);       \
        int idx00 = (yc0 * WW + xc0) * CH;                                      \
        enc[v] = (uint_t)idx00 | ((uint_t)(xc1 - xc0) << 30)                    \
                               | ((uint_t)(yc1 - yc0) << 31);                   \
        float4 wq;                                                              \
        wq.x = (1.f - ly) * (1.f - lx) * (m) * ((vy0 && vx0) ? 1.f : 0.f);      \
        wq.y = (1.f - ly) * lx         * (m) * ((vy0 && vx1) ? 1.f : 0.f);      \
        wq.z = ly         * (1.f - lx) * (m) * ((vy1 && vx0) ? 1.f : 0.f);      \
        wq.w = ly         * lx         * (m) * ((vy1 && vx1) ? 1.f : 0.f);      \
        *(float4*)(&psf[(v) * 4]) = wq;                                         \
    }
    PARAM_STORE(tid,       dy0, dx0, m0);
    PARAM_STORE(tid + 256, dy1, dx1, m1);
    if (tid < 64) PARAM_STORE(tid + 512, dy2, dx2, m2);
#undef PARAM_STORE
    __syncthreads();

    // ============ Phase 2: deformed gather + main MFMA ============
    int wr = wid & 1;            // pixel half
    int wc = wid >> 1;           // oc half
    float4v acc[2][4];
#pragma unroll
    for (int i = 0; i < 2; i++)
#pragma unroll
        for (int j = 0; j < 4; j++)
            acc[i][j] = (float4v){0.f, 0.f, 0.f, 0.f};

    for (int chunk = 0; chunk < 4; ++chunk) {
        int c0 = chunk * 32;
#pragma unroll
        for (int i = 0; i < 9; ++i) {
            int v   = tid + i * 256;
            int t   = v >> 8;
            int r   = v & 255;
            int pix = r >> 2, cg = r & 3;
            int pv  = pix * 9 + t;
            uint_t e  = enc[pv];
            float4 wq = *(const float4*)(&psf[pv * 4]);
            int idx00 = (int)(e & 0x3FFFFFFFu);
            int dxo   = (int)((e >> 30) & 1u) << 7;    // +CH
            int dyo   = (int)(e >> 31) << 13;          // +WW*CH
            const ushort_t* bp = xb_img + idx00 + c0 + cg * 8;
            uint4 u00 = *(const uint4*)(bp);
            uint4 u01 = *(const uint4*)(bp + dxo);
            uint4 u10 = *(const uint4*)(bp + dyo);
            uint4 u11 = *(const uint4*)(bp + dxo + dyo);
            uint4 res;
#define CMB(fld) {                                                         \
            float lo = wq.x * bf2f(u00.fld & 0xffffu);                     \
            lo = fmaf(wq.y, bf2f(u01.fld & 0xffffu), lo);                  \
            lo = fmaf(wq.z, bf2f(u10.fld & 0xffffu), lo);                  \
            lo = fmaf(wq.w, bf2f(u11.fld & 0xffffu), lo);                  \
            float hi = wq.x * bf2f_hi(u00.fld);                            \
            hi = fmaf(wq.y, bf2f_hi(u01.fld), hi);                        \
            hi = fmaf(wq.z, bf2f_hi(u10.fld), hi);                        \
            hi = fmaf(wq.w, bf2f_hi(u11.fld), hi);                        \
            res.fld = (uint_t)f2bf(lo) | ((uint_t)f2bf(hi) << 16); }
            CMB(x); CMB(y); CMB(z); CMB(w);
#undef CMB
            *(uint4*)(&s[pix * RSE + swz(pix, t * 32 + cg * 8)]) = res;
        }
        __syncthreads();

        const ushort_t* wb = w2 + (size_t)chunk * 36 * 1024;
        __builtin_amdgcn_s_setprio(1);
#pragma unroll 3
        for (int ks = 0; ks < 9; ++ks) {
            int rowA = wr * 32 + ll;
            int off  = swz(rowA, ks * 32 + lh * 8);
            short8v a0 = *(const short8v*)(&s[rowA * RSE + off]);
            short8v a1 = *(const short8v*)(&s[(rowA + 16) * RSE + off]);
            const ushort_t* wp = wb + (ks * 4 + lh) * 1024 + (wc * 64 + ll) * 8;
            short8v b0 = *(const short8v*)(wp);
            short8v b1 = *(const short8v*)(wp + 128);
            short8v b2 = *(const short8v*)(wp + 256);
            short8v b3 = *(const short8v*)(wp + 384);
            acc[0][0] = __builtin_amdgcn_mfma_f32_16x16x32_bf16(a0, b0, acc[0][0], 0, 0, 0);
            acc[0][1] = __builtin_amdgcn_mfma_f32_16x16x32_bf16(a0, b1, acc[0][1], 0, 0, 0);
            acc[0][2] = __builtin_amdgcn_mfma_f32_16x16x32_bf16(a0, b2, acc[0][2], 0, 0, 0);
            acc[0][3] = __builtin_amdgcn_mfma_f32_16x16x32_bf16(a0, b3, acc[0][3], 0, 0, 0);
            acc[1][0] = __builtin_amdgcn_mfma_f32_16x16x32_bf16(a1, b0, acc[1][0], 0, 0, 0);
            acc[1][1] = __builtin_amdgcn_mfma_f32_16x16x32_bf16(a1, b1, acc[1][1], 0, 0, 0);
            acc[1][2] = __builtin_amdgcn_mfma_f32_16x16x32_bf16(a1, b2, acc[1][2], 0, 0, 0);
            acc[1][3] = __builtin_amdgcn_mfma_f32_16x16x32_bf16(a1, b3, acc[1][3], 0, 0, 0);
        }
        __builtin_amdgcn_s_setprio(0);
        __syncthreads();
    }

    // Epilogue: D col(oc)=ll, row(pix)=lh*4+reg
#pragma unroll
    for (int pi = 0; pi < 2; ++pi) {
#pragma unroll
        for (int oj = 0; oj < 4; ++oj) {
            int oc = wc * 64 + oj * 16 + ll;
            int w  = wr * 32 + pi * 16 + lh * 4;
            float bv = bias[oc];
            float4v a = acc[pi][oj];
            float* op = out + (((size_t)(b * CH + oc)) << 12) + (h << 6) + w;
            *(float4*)op = make_float4(a[0] + bv, a[1] + bv, a[2] + bv, a[3] + bv);
        }
    }
}

extern "C" void kernel_launch(void* const* d_in, const int* in_sizes, int n_in,
                              void* d_out, int out_size, void* d_ws, size_t ws_size,
                              hipStream_t stream) {
    const float* x        = (const float*)d_in[0];
    const float* offset_w = (const float*)d_in[1];
    const float* offset_b = (const float*)d_in[2];
    const float* mask_w   = (const float*)d_in[3];
    const float* mask_b   = (const float*)d_in[4];
    const float* weight   = (const float*)d_in[5];
    const float* bias     = (const float*)d_in[6];
    float* out = (float*)d_out;

    char* ws = (char*)d_ws;
    ushort_t* x_bf = (ushort_t*)ws;                        // 8,388,608 B
    ushort_t* w2   = (ushort_t*)(ws + 8388608);            //   294,912 B
    ushort_t* w2om = (ushort_t*)(ws + 8388608 + 294912);   //    73,728 B

    int wblocks = ((CH + 32) * KDIM + 255) / 256;          // 720
    k_prep_all<<<4096 + wblocks, 256, 0, stream>>>(x, weight, offset_w, mask_w,
                                                   x_bf, w2, w2om);

    int npix = BATCH * HWSZ;                               // 32768
    k_fused<<<npix / DP, 256, 0, stream>>>(x_bf, w2, w2om, offset_b, mask_b, bias, out);
}